// Round 9
// baseline (1497.269 us; speedup 1.0000x reference)
//
#include <hip/hip_runtime.h>

typedef __attribute__((ext_vector_type(8))) short bf16x8;
typedef __attribute__((ext_vector_type(4))) float f32x4;
typedef __attribute__((ext_vector_type(2))) unsigned int u32x2;
typedef __attribute__((ext_vector_type(4))) unsigned int u32x4;

#define MFMA16(a,b,c) __builtin_amdgcn_mfma_f32_16x16x32_bf16(a,b,c,0,0,0)
#define A_GELU 0.7978845608028654f

// ---- LDS byte offsets (all 16B aligned) ----
#define OFF_W1B   0u        // ushort[256][72]  W1 mirror [n=hf4][m=f]
#define OFF_W2F   36864u    // ushort[64][264]  W2 mirror [f][hf4]
#define OFF_W2T   70656u    // ushort[256][72]  W2 transposed mirror [hf4][f]
#define OFF_XK    107520u   // ushort[16][72]   xk row-major
#define OFF_XQ    109824u   // ushort[16][72]
#define OFF_XKT   112128u   // ushort[64][24]   xk col-major [f][r], r<16
#define OFF_X2    115200u   // ushort[16][264]
#define OFF_X2B   123648u   // ushort[16][264]
#define OFF_DZ2B  132096u   // ushort[16][72]
#define OFF_DZ1CT 134400u   // ushort[256][24]  dZ1 col-major [n][r]
#define OFF_DZ2CT 146688u   // ushort[64][24]
#define OFF_M1    149760u   // ushort[16][24]
#define OFF_M2    150528u   // ushort[16][24]
#define OFF_Z2F   151296u   // float[16][66]  Z2 partial (kh==1)
#define OFF_Z2G   155520u   // float[16][66]  Z2 partial (kh==0)
#define OFF_TGT   159744u   // ushort[16][72]  xv-xk bf16
#define OFF_B2    162048u   // float[2][64]
#define OFF_COEF  162560u   // float[16]
#define OFF_CL    162624u   // float[1] (+pad)
#define SMEM_BYTES 162640u

__device__ __forceinline__ float fast_tanh(float u){
    float e = __expf(2.0f*u);
    return 1.0f - 2.0f/(e + 1.0f);
}
__device__ __forceinline__ float gelu_f(float x){
    float t = fast_tanh(A_GELU*(x + 0.044715f*x*x*x));
    return 0.5f*x*(1.0f+t);
}
__device__ __forceinline__ float dgelu_f(float x){
    float x2 = x*x;
    float t = fast_tanh(A_GELU*x*(1.0f + 0.044715f*x2));
    return 0.5f*x*((1.0f-t*t)*(A_GELU + 0.1070322243f*x2)) + 0.5f*(1.0f+t);
}
__device__ __forceinline__ short f2bf(float f){
    unsigned u = __builtin_bit_cast(unsigned, f);
    u += 0x7FFFu + ((u >> 16) & 1u);
    return (short)(u >> 16);
}
__device__ __forceinline__ float bf2f(unsigned short s){
    unsigned u = ((unsigned)s) << 16;
    return __builtin_bit_cast(float, u);
}
__device__ __forceinline__ unsigned pkbf(float a, float b){
    unsigned r;
    asm("v_cvt_pk_bf16_f32 %0, %1, %2" : "=v"(r) : "v"(a), "v"(b));
    return r;
}
__device__ __forceinline__ bf16x8 ldfrag(const unsigned short* p){
    return *(const bf16x8*)p;
}
// K=16 operand in a K=32 MFMA: k>=16 slots (hi>=2 lanes) supply zeros on both
// A and B, so those products are exactly 0.
__device__ __forceinline__ bf16x8 ldmask16(const unsigned short* row, int hi){
    bf16x8 r = {0,0,0,0,0,0,0,0};
    if (hi < 2) r = *(const bf16x8*)(row + hi*8);
    return r;
}

__global__ __launch_bounds__(512, 1)
void ttt_m2(const float* __restrict__ XQ, const float* __restrict__ XK,
            const float* __restrict__ XV, const float* __restrict__ coeff,
            const float* __restrict__ coeff_last,
            const float* __restrict__ W1g, const float* __restrict__ b1g,
            const float* __restrict__ W2g, const float* __restrict__ b2g,
            const float* __restrict__ gammag, const float* __restrict__ betag,
            float* __restrict__ out)
{
    const int h  = blockIdx.x;      // head 0..63
    const int t  = threadIdx.x;     // 0..511
    const int l  = t & 63;          // lane
    const int w  = t >> 6;          // wave 0..7
    const int lo = l & 15;
    const int hi = l >> 4;          // 0..3

    extern __shared__ char smem[];
    unsigned short* sW1bu  = (unsigned short*)(smem + OFF_W1B);
    unsigned short* sW2fu  = (unsigned short*)(smem + OFF_W2F);
    unsigned short* sW2T   = (unsigned short*)(smem + OFF_W2T);
    unsigned short* sxku   = (unsigned short*)(smem + OFF_XK);
    unsigned short* sxqu   = (unsigned short*)(smem + OFF_XQ);
    unsigned short* sxkT   = (unsigned short*)(smem + OFF_XKT);
    unsigned short* sX2u   = (unsigned short*)(smem + OFF_X2);
    unsigned short* sX2bu  = (unsigned short*)(smem + OFF_X2B);
    unsigned short* sdZ2bu = (unsigned short*)(smem + OFF_DZ2B);
    unsigned short* sdZ1ct = (unsigned short*)(smem + OFF_DZ1CT);
    unsigned short* sdZ2ct = (unsigned short*)(smem + OFF_DZ2CT);
    unsigned short* sM1u   = (unsigned short*)(smem + OFF_M1);
    unsigned short* sM2u   = (unsigned short*)(smem + OFF_M2);
    float* sZ2f  = (float*)(smem + OFF_Z2F);
    float* sZ2g  = (float*)(smem + OFF_Z2G);
    unsigned short* stgtu = (unsigned short*)(smem + OFF_TGT);
    float* b2f   = (float*)(smem + OFF_B2);
    float* scoef = (float*)(smem + OFF_COEF);
    float* sCL   = (float*)(smem + OFF_CL);

    const int base1 = h*16384;   // W1 [64][256]
    const int base2 = h*16384;   // W2 [256][64]

    // ---------------- init ----------------
    float mW1[4][2][4];   // W1[m=mt*16+hi*4+reg][n=(2w+tix)*16+lo]
    float mW2[2][4][4];   // W2[m=(2w+mi)*16+hi*4+reg][n=nt*16+lo]
    float mW2T[4][2][4];  // W2T[f=ft*16+hi*4+reg][hf=(2w+tix)*16+lo]
    #pragma unroll
    for (int mt = 0; mt < 4; ++mt)
      #pragma unroll
      for (int tix = 0; tix < 2; ++tix)
        #pragma unroll
        for (int reg = 0; reg < 4; ++reg) {
            const int m = mt*16 + hi*4 + reg, n = (2*w + tix)*16 + lo;
            mW1[mt][tix][reg] = W1g[base1 + m*256 + n];
        }
    #pragma unroll
    for (int mi = 0; mi < 2; ++mi)
      #pragma unroll
      for (int nt = 0; nt < 4; ++nt)
        #pragma unroll
        for (int reg = 0; reg < 4; ++reg) {
            const int m = (2*w + mi)*16 + hi*4 + reg, n = nt*16 + lo;
            mW2[mi][nt][reg] = W2g[base2 + m*64 + n];
        }
    #pragma unroll
    for (int ft = 0; ft < 4; ++ft)
      #pragma unroll
      for (int tix = 0; tix < 2; ++tix)
        #pragma unroll
        for (int reg = 0; reg < 4; ++reg) {
            const int f = ft*16 + hi*4 + reg, hf = (2*w + tix)*16 + lo;
            mW2T[ft][tix][reg] = W2g[base2 + hf*64 + f];
        }
    float b1reg[2];
    b1reg[0] = b1g[h*256 + (2*w)*16 + lo];
    b1reg[1] = b1g[h*256 + (2*w+1)*16 + lo];

    // bf16 mirrors (cooperative)
    for (int i = 0; i < 32; ++i) {
        const int idx = i*512 + t;
        const int m = idx >> 8, n = idx & 255;
        sW1bu[n*72 + m] = f2bf(W1g[base1 + idx]);
    }
    for (int i = 0; i < 32; ++i) {
        const int idx = i*512 + t;
        const int hf = idx >> 6, f = idx & 63;
        const short v = f2bf(W2g[base2 + idx]);
        sW2fu[f*264 + hf] = v;
        sW2T[hf*72 + f]   = v;
    }
    if (t < 64) b2f[t] = b2g[h*64 + t];

    const float gj = gammag[(h & 15)*64 + l];
    const float bj = betag [(h & 15)*64 + l];

    // ---- stage chunk 0 (all waves, 2 rows each) ----
    {
        const int r0 = w*2;
        const float xk0 = XK[h*1024 + r0*64 + l],     xq0 = XQ[h*1024 + r0*64 + l];
        const float xk1 = XK[h*1024 + (r0+1)*64 + l], xq1 = XQ[h*1024 + (r0+1)*64 + l];
        const float xv0 = XV[h*1024 + r0*64 + l],     xv1 = XV[h*1024 + (r0+1)*64 + l];
        const unsigned pkk = pkbf(xk0, xk1), pkq = pkbf(xq0, xq1);
        const unsigned pkt = pkbf(xv0 - xk0, xv1 - xk1);
        sxku[r0*72 + l]     = (unsigned short)pkk;
        sxku[(r0+1)*72 + l] = (unsigned short)(pkk >> 16);
        sxqu[r0*72 + l]     = (unsigned short)pkq;
        sxqu[(r0+1)*72 + l] = (unsigned short)(pkq >> 16);
        *(unsigned*)&sxkT[l*24 + r0] = pkk;
        stgtu[r0*72 + l]     = (unsigned short)pkt;
        stgtu[(r0+1)*72 + l] = (unsigned short)(pkt >> 16);
        if (t < 16)  scoef[t] = coeff[h*16 + t];
        if (t == 16) sCL[0]   = coeff_last[h];
    }
    __syncthreads();                                            // B1 (chunk 0)

    for (int ci = 0; ci < 128; ++ci) {
        // ---- snapshot coeffs to regs ----
        const float clv = sCL[0];
        const float c15 = scoef[15];
        float crs[4];
        #pragma unroll
        for (int reg = 0; reg < 4; ++reg) crs[reg] = scoef[hi*4 + reg];

        // ---- prefetch next chunk globals into regs (waves 4-7) ----
        float pxk[4], pxq[4], pxv[4];
        float pcf = 0.f, pcl = 0.f;
        if (w >= 4 && ci < 127) {
            const int cb1 = (ci + 1)*65536 + h*1024;
            const int r0 = (w - 4)*4;
            #pragma unroll
            for (int i = 0; i < 4; ++i) {
                pxk[i] = XK[cb1 + (r0 + i)*64 + l];
                pxq[i] = XQ[cb1 + (r0 + i)*64 + l];
                pxv[i] = XV[cb1 + (r0 + i)*64 + l];
            }
            const int u = t - 256;
            if (u < 16)  pcf = coeff[(ci + 1)*1024 + h*16 + u];
            if (u == 16) pcl = coeff_last[(ci + 1)*64 + h];
        }

        // ---- PA: Z1 = xk@W1 + b1 ; X2 ; wave0: A1/M1' ; W2 mirror rewrites ----
        float z1s[8];
        unsigned px2[2][2];                       // packed X2 bf16 pairs, kept for PF-a
        bf16x8 afk0 = ldfrag(sxku + lo*72 + hi*8);
        bf16x8 afk1 = ldfrag(sxku + lo*72 + 32 + hi*8);
        #pragma unroll
        for (int tix = 0; tix < 2; ++tix) {
            const int n = (2*w + tix)*16 + lo;
            f32x4 acc = {b1reg[tix], b1reg[tix], b1reg[tix], b1reg[tix]};
            acc = MFMA16(afk0, ldfrag(sW1bu + n*72 + hi*8), acc);
            acc = MFMA16(afk1, ldfrag(sW1bu + n*72 + 32 + hi*8), acc);
            float g[4];
            #pragma unroll
            for (int reg = 0; reg < 4; ++reg) {
                z1s[tix*4 + reg] = acc[reg];
                g[reg] = gelu_f(acc[reg]);
            }
            const unsigned p01 = pkbf(g[0], g[1]), p23 = pkbf(g[2], g[3]);
            px2[tix][0] = p01; px2[tix][1] = p23;
            sX2u[(hi*4+0)*264 + n] = (unsigned short)p01;
            sX2u[(hi*4+1)*264 + n] = (unsigned short)(p01 >> 16);
            sX2u[(hi*4+2)*264 + n] = (unsigned short)p23;
            sX2u[(hi*4+3)*264 + n] = (unsigned short)(p23 >> 16);
        }
        if (w == 0) {   // A1 = xq@xk^T ; M1'[r][s] = (s<=r) ? -c_r*(A1+1) : 0
            bf16x8 aq0 = ldfrag(sxqu + lo*72 + hi*8);
            bf16x8 aq1 = ldfrag(sxqu + lo*72 + 32 + hi*8);
            f32x4 a1 = {0.f, 0.f, 0.f, 0.f};
            a1 = MFMA16(aq0, afk0, a1);
            a1 = MFMA16(aq1, afk1, a1);
            #pragma unroll
            for (int reg = 0; reg < 4; ++reg) {
                const int r = hi*4 + reg;
                const float v = (lo <= r) ? (-crs[reg]*(a1[reg] + 1.0f)) : 0.0f;
                sM1u[r*24 + lo] = f2bf(v);
            }
        }
        // W2 mirror rewrites from masters — both b64 now
        #pragma unroll
        for (int mi = 0; mi < 2; ++mi)
          #pragma unroll
          for (int nt = 0; nt < 4; ++nt) {
                const int n = nt*16 + lo, m0 = (2*w + mi)*16 + hi*4;
                *(u32x2*)&sW2fu[n*264 + m0] =
                    (u32x2){pkbf(mW2[mi][nt][0], mW2[mi][nt][1]),
                            pkbf(mW2[mi][nt][2], mW2[mi][nt][3])};
          }
        #pragma unroll
        for (int ft = 0; ft < 4; ++ft)
          #pragma unroll
          for (int tix = 0; tix < 2; ++tix) {
                const int hf = (2*w + tix)*16 + lo, f0 = ft*16 + hi*4;
                *(u32x2*)&sW2T[hf*72 + f0] =
                    (u32x2){pkbf(mW2T[ft][tix][0], mW2T[ft][tix][1]),
                            pkbf(mW2T[ft][tix][2], mW2T[ft][tix][3])};
          }
        __syncthreads();                                        // B2

        // ---- PB: Z2 = X2@W2 + b2 (split-K, two partial buffers) ----
        const int tile = w & 3, kh = w >> 2;
        const int nf = tile*16 + lo;
        {
            f32x4 acc;
            if (kh == 0) {
                const float b2v = b2f[(ci & 1)*64 + nf];
                acc = (f32x4){b2v, b2v, b2v, b2v};
            } else acc = (f32x4){0.f, 0.f, 0.f, 0.f};
            #pragma unroll
            for (int s = 0; s < 4; ++s) {
                const int k = (kh*4 + s)*32 + hi*8;
                acc = MFMA16(ldfrag(sX2u + lo*264 + k),
                             ldfrag(sW2fu + nf*264 + k), acc);
            }
            float* dst = (kh == 0) ? sZ2g : sZ2f;
            #pragma unroll
            for (int reg = 0; reg < 4; ++reg)
                dst[(hi*4 + reg)*66 + nf] = acc[reg];
        }
        __syncthreads();                                        // B3

        // ---- PC: LN-fused-L2 backward (merge partials) -> dZ2 ----
        {
            float dzp[2];
            #pragma unroll
            for (int i = 0; i < 2; ++i) {
                const int r = w*2 + i;
                const float z2 = sZ2f[r*66 + l] + sZ2g[r*66 + l];
                float s1 = z2, s2 = z2*z2;
                #pragma unroll
                for (int m = 1; m < 64; m <<= 1) { s1 += __shfl_xor(s1, m); s2 += __shfl_xor(s2, m); }
                const float mu   = s1*(1.0f/64.0f);
                const float var  = s2*(1.0f/64.0f) - mu*mu;
                const float rstd = rsqrtf(var + 1e-6f);
                const float xh   = (z2 - mu)*rstd;
                const float go   = gj*xh + bj - bf2f(stgtu[r*72 + l]);
                const float gg   = go*gj;
                float u1 = gg, u2 = gg*xh;
                #pragma unroll
                for (int m = 1; m < 64; m <<= 1) { u1 += __shfl_xor(u1, m); u2 += __shfl_xor(u2, m); }
                dzp[i] = (64.0f*gg - u1 - xh*u2)*(rstd*(1.0f/64.0f));
            }
            const unsigned pk = pkbf(dzp[0], dzp[1]);
            sdZ2bu[(w*2)*72 + l]   = (unsigned short)pk;
            sdZ2bu[(w*2+1)*72 + l] = (unsigned short)(pk >> 16);
            *(unsigned*)&sdZ2ct[l*24 + w*2] = pk;
        }
        __syncthreads();                                        // B4

        // ---- PD: dZ1 = (dZ2@W2^T) * dgelu(Z1) -> sdZ1ct ; b1 carry ----
        float b1old[2];
        {
            bf16x8 ad0 = ldfrag(sdZ2bu + lo*72 + hi*8);
            bf16x8 ad1 = ldfrag(sdZ2bu + lo*72 + 32 + hi*8);
            #pragma unroll
            for (int tix = 0; tix < 2; ++tix) {
                const int n = (2*w + tix)*16 + lo;              // hf col
                f32x4 acc = {0.f, 0.f, 0.f, 0.f};
                acc = MFMA16(ad0, ldfrag(sW2T + n*72 + hi*8), acc);
                acc = MFMA16(ad1, ldfrag(sW2T + n*72 + 32 + hi*8), acc);
                float dv[4], cs = 0.f;
                #pragma unroll
                for (int reg = 0; reg < 4; ++reg) {
                    dv[reg] = acc[reg]*dgelu_f(z1s[tix*4 + reg]);
                    cs += dv[reg];
                }
                *(u32x2*)&sdZ1ct[n*24 + hi*4] =
                    (u32x2){pkbf(dv[0], dv[1]), pkbf(dv[2], dv[3])};
                cs += __shfl_xor(cs, 16);
                cs += __shfl_xor(cs, 32);
                b1old[tix] = b1reg[tix];
                b1reg[tix] -= c15*cs;
            }
        }
        __syncthreads();                                        // B5

        // ---- PE: Z1bar = xq@W1 + b1old + M1'@dZ1 -> X2b ; W1 master update ----
        {
            bf16x8 aq0 = ldfrag(sxqu + lo*72 + hi*8);
            bf16x8 aq1 = ldfrag(sxqu + lo*72 + 32 + hi*8);
            bf16x8 am1 = ldmask16(sM1u + lo*24, hi);
            #pragma unroll
            for (int tix = 0; tix < 2; ++tix) {
                const int n = (2*w + tix)*16 + lo;
                f32x4 acc = {b1old[tix], b1old[tix], b1old[tix], b1old[tix]};
                acc = MFMA16(aq0, ldfrag(sW1bu + n*72 + hi*8), acc);
                acc = MFMA16(aq1, ldfrag(sW1bu + n*72 + 32 + hi*8), acc);
                acc = MFMA16(am1, ldmask16(sdZ1ct + n*24, hi), acc);
                float g[4];
                #pragma unroll
                for (int reg = 0; reg < 4; ++reg) g[reg] = gelu_f(acc[reg]);
                const unsigned p01 = pkbf(g[0], g[1]), p23 = pkbf(g[2], g[3]);
                sX2bu[(hi*4+0)*264 + n] = (unsigned short)p01;
                sX2bu[(hi*4+1)*264 + n] = (unsigned short)(p01 >> 16);
                sX2bu[(hi*4+2)*264 + n] = (unsigned short)p23;
                sX2bu[(hi*4+3)*264 + n] = (unsigned short)(p23 >> 16);
            }
            // W1 -= cl * xk^T @ dZ1  (A from sxkT frags, B from sdZ1ct frags)
            bf16x8 bz0 = ldmask16(sdZ1ct + ((2*w)*16 + lo)*24, hi);
            bf16x8 bz1 = ldmask16(sdZ1ct + ((2*w+1)*16 + lo)*24, hi);
            #pragma unroll
            for (int mt = 0; mt < 4; ++mt) {
                bf16x8 axt = ldmask16(sxkT + (mt*16 + lo)*24, hi);
                f32x4 z4 = {0.f,0.f,0.f,0.f};
                f32x4 u0 = MFMA16(axt, bz0, z4);
                f32x4 u1 = MFMA16(axt, bz1, z4);
                #pragma unroll
                for (int reg = 0; reg < 4; ++reg) {
                    mW1[mt][0][reg] -= clv*u0[reg];
                    mW1[mt][1][reg] -= clv*u1[reg];
                }
            }
        }
        __syncthreads();                                        // B6

        // ---- PF-a: W2 masters update (both layouts, shfl'd X2 frags) ;
        //      wave0 A2/M2' ; wave1 b2 carry ; W1-mirror rewrite ----
        {
            bf16x8 bz2[4];
            #pragma unroll
            for (int nt = 0; nt < 4; ++nt)
                bz2[nt] = ldmask16(sdZ2ct + (nt*16 + lo)*24, hi);
            // X2 frags via cross-lane redistribution of px2 (no LDS):
            // element j of xf[tix] = X2[r=hi*8+j][(2w+tix)*16+lo], hi<2.
            bf16x8 xf[2];
            {
                const int base = lo + 32*(hi & 1);
                #pragma unroll
                for (int tix = 0; tix < 2; ++tix) {
                    unsigned w0 = (unsigned)__shfl((int)px2[tix][0], base);
                    unsigned w1 = (unsigned)__shfl((int)px2[tix][1], base);
                    unsigned w2 = (unsigned)__shfl((int)px2[tix][0], base + 16);
                    unsigned w3 = (unsigned)__shfl((int)px2[tix][1], base + 16);
                    if (hi >= 2) { w0 = 0; w1 = 0; w2 = 0; w3 = 0; }
                    xf[tix] = __builtin_bit_cast(bf16x8, (u32x4){w0, w1, w2, w3});
                }
            }
            #pragma unroll
            for (int mi = 0; mi < 2; ++mi)
                #pragma unroll
                for (int nt = 0; nt < 4; ++nt) {
                    f32x4 z4 = {0.f,0.f,0.f,0.f};
                    f32x4 u = MFMA16(xf[mi], bz2[nt], z4);
                    #pragma unroll
                    for (int reg = 0; reg < 4; ++reg)
                        mW2[mi][nt][reg] -= clv*u[reg];
                }
            #pragma unroll
            for (int ft = 0; ft < 4; ++ft)
                #pragma unroll
                for (int tix = 0; tix < 2; ++tix) {
                    f32x4 z4 = {0.f,0.f,0.f,0.f};
                    f32x4 u = MFMA16(bz2[ft], xf[tix], z4);
                    #pragma unroll
                    for (int reg = 0; reg < 4; ++reg)
                        mW2T[ft][tix][reg] -= clv*u[reg];
                }
            if (w == 0) {   // A2 = X2b@X2^T ; M2'
                f32x4 a2 = {0.f,0.f,0.f,0.f};
                #pragma unroll
                for (int ks = 0; ks < 8; ++ks) {
                    const int k = ks*32 + hi*8;
                    a2 = MFMA16(ldfrag(sX2bu + lo*264 + k),
                                ldfrag(sX2u + lo*264 + k), a2);
                }
                #pragma unroll
                for (int reg = 0; reg < 4; ++reg) {
                    const int r = hi*4 + reg;
                    const float v = (lo <= r) ? (-crs[reg]*(a2[reg] + 1.0f)) : 0.0f;
                    sM2u[r*24 + lo] = f2bf(v);
                }
            }
            if (w == 1) {   // b2 carry
                float cs = 0.f;
                #pragma unroll
                for (int k = 0; k < 16; ++k) cs += bf2f(sdZ2bu[k*72 + l]);
                b2f[((ci + 1) & 1)*64 + l] = b2f[(ci & 1)*64 + l] - c15*cs;
            }
            // W1-mirror rewrite (sW1bu last read in PE)
            #pragma unroll
            for (int mt = 0; mt < 4; ++mt)
              #pragma unroll
              for (int tix = 0; tix < 2; ++tix) {
                    const int n = (2*w + tix)*16 + lo, m0 = mt*16 + hi*4;
                    *(u32x2*)&sW1bu[n*72 + m0] =
                        (u32x2){pkbf(mW1[mt][tix][0], mW1[mt][tix][1]),
                                pkbf(mW1[mt][tix][2], mW1[mt][tix][3])};
              }
        }
        __syncthreads();                                        // B7

        // ---- PF-b: waves 0-3 Z2bar full-K + out ; waves 4-7 stage next chunk ----
        if (w < 4) {
            const int nf2 = w*16 + lo;
            const float b2v = b2f[(ci & 1)*64 + nf2];
            f32x4 acc = {b2v, b2v, b2v, b2v};
            #pragma unroll
            for (int s = 0; s < 8; ++s) {
                const int k0 = s*32 + hi*8;
                acc = MFMA16(ldfrag(sX2bu + lo*264 + k0),
                             ldfrag(sW2fu + nf2*264 + k0), acc);
            }
            acc = MFMA16(ldmask16(sM2u + lo*24, hi),
                         ldmask16(sdZ2ct + nf2*24, hi), acc);
            #pragma unroll
            for (int reg = 0; reg < 4; ++reg)
                out[h*131072 + (ci*16 + hi*4 + reg)*64 + nf2] = acc[reg];
        } else if (ci < 127) {
            const int r0 = (w - 4)*4;
            #pragma unroll
            for (int p = 0; p < 2; ++p) {
                const int r = r0 + 2*p;
                const unsigned pkk = pkbf(pxk[2*p], pxk[2*p+1]);
                const unsigned pkq = pkbf(pxq[2*p], pxq[2*p+1]);
                const unsigned pkt = pkbf(pxv[2*p] - pxk[2*p], pxv[2*p+1] - pxk[2*p+1]);
                sxku[r*72 + l]     = (unsigned short)pkk;
                sxku[(r+1)*72 + l] = (unsigned short)(pkk >> 16);
                sxqu[r*72 + l]     = (unsigned short)pkq;
                sxqu[(r+1)*72 + l] = (unsigned short)(pkq >> 16);
                *(unsigned*)&sxkT[l*24 + r] = pkk;
                stgtu[r*72 + l]     = (unsigned short)pkt;
                stgtu[(r+1)*72 + l] = (unsigned short)(pkt >> 16);
            }
            const int u = t - 256;
            if (u < 16)  scoef[u] = pcf;
            if (u == 16) sCL[0]   = pcl;
        }
        __syncthreads();                                        // B1 (next chunk)
    }
}

extern "C" void kernel_launch(void* const* d_in, const int* in_sizes, int n_in,
                              void* d_out, int out_size, void* d_ws, size_t ws_size,
                              hipStream_t stream) {
    const float* XQ  = (const float*)d_in[0];
    const float* XK  = (const float*)d_in[1];
    const float* XV  = (const float*)d_in[2];
    const float* cf  = (const float*)d_in[3];
    const float* cfl = (const float*)d_in[4];
    const float* W1  = (const float*)d_in[5];
    const float* b1  = (const float*)d_in[6];
    const float* W2  = (const float*)d_in[7];
    const float* b2  = (const float*)d_in[8];
    const float* gam = (const float*)d_in[9];
    const float* bet = (const float*)d_in[10];
    float* o = (float*)d_out;

    hipFuncSetAttribute((const void*)ttt_m2,
                        hipFuncAttributeMaxDynamicSharedMemorySize, SMEM_BYTES);
    ttt_m2<<<64, 512, SMEM_BYTES, stream>>>(XQ, XK, XV, cf, cfl, W1, b1, W2, b2, gam, bet, o);
}

// Round 10
// 870.653 us; speedup vs baseline: 1.7197x; 1.7197x over previous
//
#include <hip/hip_runtime.h>

typedef __attribute__((ext_vector_type(8))) short bf16x8;
typedef __attribute__((ext_vector_type(4))) float f32x4;
typedef __attribute__((ext_vector_type(2))) unsigned int u32x2;
typedef __attribute__((ext_vector_type(4))) unsigned int u32x4;

#define MFMA16(a,b,c) __builtin_amdgcn_mfma_f32_16x16x32_bf16(a,b,c,0,0,0)
#define A_GELU 0.7978845608028654f

// ---- LDS byte offsets (all 16B aligned) ----
#define OFF_W1B   0u        // ushort[256][72]  W1 mirror [n=hf4][m=f]
#define OFF_W2F   36864u    // ushort[64][264]  W2 mirror [f][hf4]
#define OFF_W2T   70656u    // ushort[256][72]  W2 transposed mirror [hf4][f]
#define OFF_XK    107520u   // ushort[16][72]   xk row-major
#define OFF_XQ    109824u   // ushort[16][72]
#define OFF_XKT   112128u   // ushort[64][24]   xk col-major [f][r], r<16
#define OFF_X2    115200u   // ushort[16][264]
#define OFF_X2B   123648u   // ushort[16][264]
#define OFF_DZ2B  132096u   // ushort[16][72]
#define OFF_DZ1CT 134400u   // ushort[256][24]  dZ1 col-major [n][r]
#define OFF_DZ2CT 146688u   // ushort[64][24]
#define OFF_M1    149760u   // ushort[16][24]
#define OFF_M2    150528u   // ushort[16][24]
#define OFF_Z2F   151296u   // float[16][66]  Z2 partial (kh==1)
#define OFF_Z2G   155520u   // float[16][66]  Z2 partial (kh==0)
#define OFF_TGT   159744u   // ushort[16][72]  xv-xk bf16
#define OFF_B2    162048u   // float[2][64]
#define OFF_COEF  162560u   // float[16]
#define OFF_CL    162624u   // float[1] (+pad)
#define SMEM_BYTES 162640u

__device__ __forceinline__ float fast_tanh(float u){
    float e = __expf(2.0f*u);
    return 1.0f - 2.0f/(e + 1.0f);
}
__device__ __forceinline__ float gelu_f(float x){
    float t = fast_tanh(A_GELU*(x + 0.044715f*x*x*x));
    return 0.5f*x*(1.0f+t);
}
__device__ __forceinline__ float dgelu_f(float x){
    float x2 = x*x;
    float t = fast_tanh(A_GELU*x*(1.0f + 0.044715f*x2));
    return 0.5f*x*((1.0f-t*t)*(A_GELU + 0.1070322243f*x2)) + 0.5f*(1.0f+t);
}
__device__ __forceinline__ short f2bf(float f){
    unsigned u = __builtin_bit_cast(unsigned, f);
    u += 0x7FFFu + ((u >> 16) & 1u);
    return (short)(u >> 16);
}
__device__ __forceinline__ float bf2f(unsigned short s){
    unsigned u = ((unsigned)s) << 16;
    return __builtin_bit_cast(float, u);
}
__device__ __forceinline__ unsigned pkbf(float a, float b){
    unsigned r;
    asm("v_cvt_pk_bf16_f32 %0, %1, %2" : "=v"(r) : "v"(a), "v"(b));
    return r;
}
__device__ __forceinline__ bf16x8 ldfrag(const unsigned short* p){
    return *(const bf16x8*)p;
}
// K=16 operand in a K=32 MFMA: k>=16 slots (hi>=2 lanes) supply zeros on both
// A and B, so those products are exactly 0.
__device__ __forceinline__ bf16x8 ldmask16(const unsigned short* row, int hi){
    bf16x8 r = {0,0,0,0,0,0,0,0};
    if (hi < 2) r = *(const bf16x8*)(row + hi*8);
    return r;
}

__global__ __launch_bounds__(512, 1)
void ttt_m2(const float* __restrict__ XQ, const float* __restrict__ XK,
            const float* __restrict__ XV, const float* __restrict__ coeff,
            const float* __restrict__ coeff_last,
            const float* __restrict__ W1g, const float* __restrict__ b1g,
            const float* __restrict__ W2g, const float* __restrict__ b2g,
            const float* __restrict__ gammag, const float* __restrict__ betag,
            float* __restrict__ out)
{
    const int h  = blockIdx.x;      // head 0..63
    const int t  = threadIdx.x;     // 0..511
    const int l  = t & 63;          // lane
    const int w  = t >> 6;          // wave 0..7
    const int lo = l & 15;
    const int hi = l >> 4;          // 0..3

    extern __shared__ char smem[];
    unsigned short* sW1bu  = (unsigned short*)(smem + OFF_W1B);
    unsigned short* sW2fu  = (unsigned short*)(smem + OFF_W2F);
    unsigned short* sW2T   = (unsigned short*)(smem + OFF_W2T);
    unsigned short* sxku   = (unsigned short*)(smem + OFF_XK);
    unsigned short* sxqu   = (unsigned short*)(smem + OFF_XQ);
    unsigned short* sxkT   = (unsigned short*)(smem + OFF_XKT);
    unsigned short* sX2u   = (unsigned short*)(smem + OFF_X2);
    unsigned short* sX2bu  = (unsigned short*)(smem + OFF_X2B);
    unsigned short* sdZ2bu = (unsigned short*)(smem + OFF_DZ2B);
    unsigned short* sdZ1ct = (unsigned short*)(smem + OFF_DZ1CT);
    unsigned short* sdZ2ct = (unsigned short*)(smem + OFF_DZ2CT);
    unsigned short* sM1u   = (unsigned short*)(smem + OFF_M1);
    unsigned short* sM2u   = (unsigned short*)(smem + OFF_M2);
    float* sZ2f  = (float*)(smem + OFF_Z2F);
    float* sZ2g  = (float*)(smem + OFF_Z2G);
    unsigned short* stgtu = (unsigned short*)(smem + OFF_TGT);
    float* b2f   = (float*)(smem + OFF_B2);
    float* scoef = (float*)(smem + OFF_COEF);
    float* sCL   = (float*)(smem + OFF_CL);

    const int base1 = h*16384;   // W1 [64][256]
    const int base2 = h*16384;   // W2 [256][64]

    // ---------------- init ----------------
    float mW1[4][2][4];   // W1[m=mt*16+hi*4+reg][n=(2w+tix)*16+lo]
    float mW2T[4][2][4];  // W2T[f=ft*16+hi*4+reg][hf=(2w+tix)*16+lo] = W2[hf][f]
    #pragma unroll
    for (int mt = 0; mt < 4; ++mt)
      #pragma unroll
      for (int tix = 0; tix < 2; ++tix)
        #pragma unroll
        for (int reg = 0; reg < 4; ++reg) {
            const int m = mt*16 + hi*4 + reg, n = (2*w + tix)*16 + lo;
            mW1[mt][tix][reg] = W1g[base1 + m*256 + n];
        }
    #pragma unroll
    for (int ft = 0; ft < 4; ++ft)
      #pragma unroll
      for (int tix = 0; tix < 2; ++tix)
        #pragma unroll
        for (int reg = 0; reg < 4; ++reg) {
            const int f = ft*16 + hi*4 + reg, hf = (2*w + tix)*16 + lo;
            mW2T[ft][tix][reg] = W2g[base2 + hf*64 + f];
        }
    float b1reg[2];
    b1reg[0] = b1g[h*256 + (2*w)*16 + lo];
    b1reg[1] = b1g[h*256 + (2*w+1)*16 + lo];

    // bf16 mirrors (cooperative)
    for (int i = 0; i < 32; ++i) {
        const int idx = i*512 + t;
        const int m = idx >> 8, n = idx & 255;
        sW1bu[n*72 + m] = f2bf(W1g[base1 + idx]);
    }
    for (int i = 0; i < 32; ++i) {
        const int idx = i*512 + t;
        const int hf = idx >> 6, f = idx & 63;
        const short v = f2bf(W2g[base2 + idx]);
        sW2fu[f*264 + hf] = v;
        sW2T[hf*72 + f]   = v;
    }
    if (t < 64) b2f[t] = b2g[h*64 + t];

    const float gj = gammag[(h & 15)*64 + l];
    const float bj = betag [(h & 15)*64 + l];

    // ---- stage chunk 0 (all waves, 2 rows each) ----
    {
        const int r0 = w*2;
        const float xk0 = XK[h*1024 + r0*64 + l],     xq0 = XQ[h*1024 + r0*64 + l];
        const float xk1 = XK[h*1024 + (r0+1)*64 + l], xq1 = XQ[h*1024 + (r0+1)*64 + l];
        const float xv0 = XV[h*1024 + r0*64 + l],     xv1 = XV[h*1024 + (r0+1)*64 + l];
        const unsigned pkk = pkbf(xk0, xk1), pkq = pkbf(xq0, xq1);
        const unsigned pkt = pkbf(xv0 - xk0, xv1 - xk1);
        sxku[r0*72 + l]     = (unsigned short)pkk;
        sxku[(r0+1)*72 + l] = (unsigned short)(pkk >> 16);
        sxqu[r0*72 + l]     = (unsigned short)pkq;
        sxqu[(r0+1)*72 + l] = (unsigned short)(pkq >> 16);
        *(unsigned*)&sxkT[l*24 + r0] = pkk;
        stgtu[r0*72 + l]     = (unsigned short)pkt;
        stgtu[(r0+1)*72 + l] = (unsigned short)(pkt >> 16);
        if (t < 16)  scoef[t] = coeff[h*16 + t];
        if (t == 16) sCL[0]   = coeff_last[h];
    }
    __syncthreads();                                            // B1 (chunk 0)

    for (int ci = 0; ci < 128; ++ci) {
        // ---- snapshot coeffs to regs ----
        const float clv = sCL[0];
        const float c15 = scoef[15];
        float crs[4];
        #pragma unroll
        for (int reg = 0; reg < 4; ++reg) crs[reg] = scoef[hi*4 + reg];

        // ---- prefetch next chunk globals into regs (waves 4-7) ----
        float pxk[4], pxq[4], pxv[4];
        float pcf = 0.f, pcl = 0.f;
        if (w >= 4 && ci < 127) {
            const int cb1 = (ci + 1)*65536 + h*1024;
            const int r0 = (w - 4)*4;
            #pragma unroll
            for (int i = 0; i < 4; ++i) {
                pxk[i] = XK[cb1 + (r0 + i)*64 + l];
                pxq[i] = XQ[cb1 + (r0 + i)*64 + l];
                pxv[i] = XV[cb1 + (r0 + i)*64 + l];
            }
            const int u = t - 256;
            if (u < 16)  pcf = coeff[(ci + 1)*1024 + h*16 + u];
            if (u == 16) pcl = coeff_last[(ci + 1)*64 + h];
        }

        // ---- PA: Z1 = xk@W1 + b1 ; X2 ; wave0: A1/M1' ; W2 mirror rewrites ----
        float z1s[8];
        unsigned px2[2][2];                       // packed X2 bf16 pairs -> PF-a
        bf16x8 afk0 = ldfrag(sxku + lo*72 + hi*8);
        bf16x8 afk1 = ldfrag(sxku + lo*72 + 32 + hi*8);
        #pragma unroll
        for (int tix = 0; tix < 2; ++tix) {
            const int n = (2*w + tix)*16 + lo;
            f32x4 acc = {b1reg[tix], b1reg[tix], b1reg[tix], b1reg[tix]};
            acc = MFMA16(afk0, ldfrag(sW1bu + n*72 + hi*8), acc);
            acc = MFMA16(afk1, ldfrag(sW1bu + n*72 + 32 + hi*8), acc);
            float g[4];
            #pragma unroll
            for (int reg = 0; reg < 4; ++reg) {
                z1s[tix*4 + reg] = acc[reg];
                g[reg] = gelu_f(acc[reg]);
            }
            const unsigned p01 = pkbf(g[0], g[1]), p23 = pkbf(g[2], g[3]);
            px2[tix][0] = p01; px2[tix][1] = p23;
            sX2u[(hi*4+0)*264 + n] = (unsigned short)p01;
            sX2u[(hi*4+1)*264 + n] = (unsigned short)(p01 >> 16);
            sX2u[(hi*4+2)*264 + n] = (unsigned short)p23;
            sX2u[(hi*4+3)*264 + n] = (unsigned short)(p23 >> 16);
        }
        if (w == 0) {   // A1 = xq@xk^T ; M1'[r][s] = (s<=r) ? -c_r*(A1+1) : 0
            bf16x8 aq0 = ldfrag(sxqu + lo*72 + hi*8);
            bf16x8 aq1 = ldfrag(sxqu + lo*72 + 32 + hi*8);
            f32x4 a1 = {0.f, 0.f, 0.f, 0.f};
            a1 = MFMA16(aq0, afk0, a1);
            a1 = MFMA16(aq1, afk1, a1);
            #pragma unroll
            for (int reg = 0; reg < 4; ++reg) {
                const int r = hi*4 + reg;
                const float v = (lo <= r) ? (-crs[reg]*(a1[reg] + 1.0f)) : 0.0f;
                sM1u[r*24 + lo] = f2bf(v);
            }
        }
        // W2 mirror rewrites from mW2T masters:
        //   sW2T gets b64 stores, sW2fu gets scalar stores (2-way banks)
        #pragma unroll
        for (int ft = 0; ft < 4; ++ft)
          #pragma unroll
          for (int tix = 0; tix < 2; ++tix) {
                const int hf = (2*w + tix)*16 + lo, f0 = ft*16 + hi*4;
                const unsigned p01 = pkbf(mW2T[ft][tix][0], mW2T[ft][tix][1]);
                const unsigned p23 = pkbf(mW2T[ft][tix][2], mW2T[ft][tix][3]);
                *(u32x2*)&sW2T[hf*72 + f0] = (u32x2){p01, p23};
                sW2fu[(f0+0)*264 + hf] = (unsigned short)p01;
                sW2fu[(f0+1)*264 + hf] = (unsigned short)(p01 >> 16);
                sW2fu[(f0+2)*264 + hf] = (unsigned short)p23;
                sW2fu[(f0+3)*264 + hf] = (unsigned short)(p23 >> 16);
          }
        __syncthreads();                                        // B2

        // ---- PB: Z2 = X2@W2 + b2 (split-K, two partial buffers) ----
        const int tile = w & 3, kh = w >> 2;
        const int nf = tile*16 + lo;
        {
            f32x4 acc;
            if (kh == 0) {
                const float b2v = b2f[(ci & 1)*64 + nf];
                acc = (f32x4){b2v, b2v, b2v, b2v};
            } else acc = (f32x4){0.f, 0.f, 0.f, 0.f};
            #pragma unroll
            for (int s = 0; s < 4; ++s) {
                const int k = (kh*4 + s)*32 + hi*8;
                acc = MFMA16(ldfrag(sX2u + lo*264 + k),
                             ldfrag(sW2fu + nf*264 + k), acc);
            }
            float* dst = (kh == 0) ? sZ2g : sZ2f;
            #pragma unroll
            for (int reg = 0; reg < 4; ++reg)
                dst[(hi*4 + reg)*66 + nf] = acc[reg];
        }
        __syncthreads();                                        // B3

        // ---- PC: LN-fused-L2 backward (merge partials) -> dZ2 ----
        {
            float dzp[2];
            #pragma unroll
            for (int i = 0; i < 2; ++i) {
                const int r = w*2 + i;
                const float z2 = sZ2f[r*66 + l] + sZ2g[r*66 + l];
                float s1 = z2, s2 = z2*z2;
                #pragma unroll
                for (int m = 1; m < 64; m <<= 1) { s1 += __shfl_xor(s1, m); s2 += __shfl_xor(s2, m); }
                const float mu   = s1*(1.0f/64.0f);
                const float var  = s2*(1.0f/64.0f) - mu*mu;
                const float rstd = rsqrtf(var + 1e-6f);
                const float xh   = (z2 - mu)*rstd;
                const float go   = gj*xh + bj - bf2f(stgtu[r*72 + l]);
                const float gg   = go*gj;
                float u1 = gg, u2 = gg*xh;
                #pragma unroll
                for (int m = 1; m < 64; m <<= 1) { u1 += __shfl_xor(u1, m); u2 += __shfl_xor(u2, m); }
                dzp[i] = (64.0f*gg - u1 - xh*u2)*(rstd*(1.0f/64.0f));
            }
            const unsigned pk = pkbf(dzp[0], dzp[1]);
            sdZ2bu[(w*2)*72 + l]   = (unsigned short)pk;
            sdZ2bu[(w*2+1)*72 + l] = (unsigned short)(pk >> 16);
            *(unsigned*)&sdZ2ct[l*24 + w*2] = pk;
        }
        __syncthreads();                                        // B4

        // ---- PD: dZ1 = (dZ2@W2^T) * dgelu(Z1) -> sdZ1ct ; b1 carry ----
        float b1old[2];
        {
            bf16x8 ad0 = ldfrag(sdZ2bu + lo*72 + hi*8);
            bf16x8 ad1 = ldfrag(sdZ2bu + lo*72 + 32 + hi*8);
            #pragma unroll
            for (int tix = 0; tix < 2; ++tix) {
                const int n = (2*w + tix)*16 + lo;              // hf col
                f32x4 acc = {0.f, 0.f, 0.f, 0.f};
                acc = MFMA16(ad0, ldfrag(sW2T + n*72 + hi*8), acc);
                acc = MFMA16(ad1, ldfrag(sW2T + n*72 + 32 + hi*8), acc);
                float dv[4], cs = 0.f;
                #pragma unroll
                for (int reg = 0; reg < 4; ++reg) {
                    dv[reg] = acc[reg]*dgelu_f(z1s[tix*4 + reg]);
                    cs += dv[reg];
                }
                *(u32x2*)&sdZ1ct[n*24 + hi*4] =
                    (u32x2){pkbf(dv[0], dv[1]), pkbf(dv[2], dv[3])};
                cs += __shfl_xor(cs, 16);
                cs += __shfl_xor(cs, 32);
                b1old[tix] = b1reg[tix];
                b1reg[tix] -= c15*cs;
            }
        }
        __syncthreads();                                        // B5

        // ---- PE: Z1bar = xq@W1 + b1old + M1'@dZ1 -> X2b ; W1 master update ----
        {
            bf16x8 aq0 = ldfrag(sxqu + lo*72 + hi*8);
            bf16x8 aq1 = ldfrag(sxqu + lo*72 + 32 + hi*8);
            bf16x8 am1 = ldmask16(sM1u + lo*24, hi);
            #pragma unroll
            for (int tix = 0; tix < 2; ++tix) {
                const int n = (2*w + tix)*16 + lo;
                f32x4 acc = {b1old[tix], b1old[tix], b1old[tix], b1old[tix]};
                acc = MFMA16(aq0, ldfrag(sW1bu + n*72 + hi*8), acc);
                acc = MFMA16(aq1, ldfrag(sW1bu + n*72 + 32 + hi*8), acc);
                acc = MFMA16(am1, ldmask16(sdZ1ct + n*24, hi), acc);
                float g[4];
                #pragma unroll
                for (int reg = 0; reg < 4; ++reg) g[reg] = gelu_f(acc[reg]);
                const unsigned p01 = pkbf(g[0], g[1]), p23 = pkbf(g[2], g[3]);
                sX2bu[(hi*4+0)*264 + n] = (unsigned short)p01;
                sX2bu[(hi*4+1)*264 + n] = (unsigned short)(p01 >> 16);
                sX2bu[(hi*4+2)*264 + n] = (unsigned short)p23;
                sX2bu[(hi*4+3)*264 + n] = (unsigned short)(p23 >> 16);
            }
            // W1 -= cl * xk^T @ dZ1  (A from sxkT frags, B from sdZ1ct frags)
            bf16x8 bz0 = ldmask16(sdZ1ct + ((2*w)*16 + lo)*24, hi);
            bf16x8 bz1 = ldmask16(sdZ1ct + ((2*w+1)*16 + lo)*24, hi);
            #pragma unroll
            for (int mt = 0; mt < 4; ++mt) {
                bf16x8 axt = ldmask16(sxkT + (mt*16 + lo)*24, hi);
                f32x4 z4 = {0.f,0.f,0.f,0.f};
                f32x4 u0 = MFMA16(axt, bz0, z4);
                f32x4 u1 = MFMA16(axt, bz1, z4);
                #pragma unroll
                for (int reg = 0; reg < 4; ++reg) {
                    mW1[mt][0][reg] -= clv*u0[reg];
                    mW1[mt][1][reg] -= clv*u1[reg];
                }
            }
        }
        __syncthreads();                                        // B6

        // ---- PF-a: W2T master update via shfl'd X2 frags ;
        //      wave0 A2/M2' ; wave1 b2 carry ; W1-mirror rewrite ----
        {
            bf16x8 bz2[4];
            #pragma unroll
            for (int nt = 0; nt < 4; ++nt)
                bz2[nt] = ldmask16(sdZ2ct + (nt*16 + lo)*24, hi);
            // X2 frags via cross-lane redistribution of px2 (no LDS):
            // element j of xf[tix] = X2[r=hi*8+j][(2w+tix)*16+lo], hi<2.
            bf16x8 xf[2];
            {
                const int base = lo + 32*(hi & 1);
                #pragma unroll
                for (int tix = 0; tix < 2; ++tix) {
                    unsigned w0 = (unsigned)__shfl((int)px2[tix][0], base);
                    unsigned w1 = (unsigned)__shfl((int)px2[tix][1], base);
                    unsigned w2 = (unsigned)__shfl((int)px2[tix][0], base + 16);
                    unsigned w3 = (unsigned)__shfl((int)px2[tix][1], base + 16);
                    if (hi >= 2) { w0 = 0; w1 = 0; w2 = 0; w3 = 0; }
                    xf[tix] = __builtin_bit_cast(bf16x8, (u32x4){w0, w1, w2, w3});
                }
            }
            // W2T -= cl * (dZ2^T @ X2): A = dZ2 col-major frags, B = xf
            #pragma unroll
            for (int ft = 0; ft < 4; ++ft)
                #pragma unroll
                for (int tix = 0; tix < 2; ++tix) {
                    f32x4 z4 = {0.f,0.f,0.f,0.f};
                    f32x4 u = MFMA16(bz2[ft], xf[tix], z4);
                    #pragma unroll
                    for (int reg = 0; reg < 4; ++reg)
                        mW2T[ft][tix][reg] -= clv*u[reg];
                }
            if (w == 0) {   // A2 = X2b@X2^T ; M2'
                f32x4 a2 = {0.f,0.f,0.f,0.f};
                #pragma unroll
                for (int ks = 0; ks < 8; ++ks) {
                    const int k = ks*32 + hi*8;
                    a2 = MFMA16(ldfrag(sX2bu + lo*264 + k),
                                ldfrag(sX2u + lo*264 + k), a2);
                }
                #pragma unroll
                for (int reg = 0; reg < 4; ++reg) {
                    const int r = hi*4 + reg;
                    const float v = (lo <= r) ? (-crs[reg]*(a2[reg] + 1.0f)) : 0.0f;
                    sM2u[r*24 + lo] = f2bf(v);
                }
            }
            if (w == 1) {   // b2 carry (contiguous b128 reads of dZ2 col l)
                bf16x8 c0 = ldfrag(sdZ2ct + l*24);
                bf16x8 c1 = ldfrag(sdZ2ct + l*24 + 8);
                float cs = 0.f;
                #pragma unroll
                for (int j = 0; j < 8; ++j)
                    cs += bf2f((unsigned short)c0[j]) + bf2f((unsigned short)c1[j]);
                b2f[((ci + 1) & 1)*64 + l] = b2f[(ci & 1)*64 + l] - c15*cs;
            }
            // W1-mirror rewrite (sW1bu last read in PE)
            #pragma unroll
            for (int mt = 0; mt < 4; ++mt)
              #pragma unroll
              for (int tix = 0; tix < 2; ++tix) {
                    const int n = (2*w + tix)*16 + lo, m0 = mt*16 + hi*4;
                    *(u32x2*)&sW1bu[n*72 + m0] =
                        (u32x2){pkbf(mW1[mt][tix][0], mW1[mt][tix][1]),
                                pkbf(mW1[mt][tix][2], mW1[mt][tix][3])};
              }
        }
        __syncthreads();                                        // B7

        // ---- PF-b: waves 0-3 Z2bar full-K + out ; waves 4-7 stage next chunk ----
        if (w < 4) {
            const int nf2 = w*16 + lo;
            const float b2v = b2f[(ci & 1)*64 + nf2];
            f32x4 acc = {b2v, b2v, b2v, b2v};
            #pragma unroll
            for (int s = 0; s < 8; ++s) {
                const int k0 = s*32 + hi*8;
                acc = MFMA16(ldfrag(sX2bu + lo*264 + k0),
                             ldfrag(sW2fu + nf2*264 + k0), acc);
            }
            acc = MFMA16(ldmask16(sM2u + lo*24, hi),
                         ldmask16(sdZ2ct + nf2*24, hi), acc);
            #pragma unroll
            for (int reg = 0; reg < 4; ++reg)
                out[h*131072 + (ci*16 + hi*4 + reg)*64 + nf2] = acc[reg];
        } else if (ci < 127) {
            const int r0 = (w - 4)*4;
            #pragma unroll
            for (int p = 0; p < 2; ++p) {
                const int r = r0 + 2*p;
                const unsigned pkk = pkbf(pxk[2*p], pxk[2*p+1]);
                const unsigned pkq = pkbf(pxq[2*p], pxq[2*p+1]);
                const unsigned pkt = pkbf(pxv[2*p] - pxk[2*p], pxv[2*p+1] - pxk[2*p+1]);
                sxku[r*72 + l]     = (unsigned short)pkk;
                sxku[(r+1)*72 + l] = (unsigned short)(pkk >> 16);
                sxqu[r*72 + l]     = (unsigned short)pkq;
                sxqu[(r+1)*72 + l] = (unsigned short)(pkq >> 16);
                *(unsigned*)&sxkT[l*24 + r] = pkk;
                stgtu[r*72 + l]     = (unsigned short)pkt;
                stgtu[(r+1)*72 + l] = (unsigned short)(pkt >> 16);
            }
            const int u = t - 256;
            if (u < 16)  scoef[u] = pcf;
            if (u == 16) sCL[0]   = pcl;
        }
        __syncthreads();                                        // B1 (next chunk)
    }
}

extern "C" void kernel_launch(void* const* d_in, const int* in_sizes, int n_in,
                              void* d_out, int out_size, void* d_ws, size_t ws_size,
                              hipStream_t stream) {
    const float* XQ  = (const float*)d_in[0];
    const float* XK  = (const float*)d_in[1];
    const float* XV  = (const float*)d_in[2];
    const float* cf  = (const float*)d_in[3];
    const float* cfl = (const float*)d_in[4];
    const float* W1  = (const float*)d_in[5];
    const float* b1  = (const float*)d_in[6];
    const float* W2  = (const float*)d_in[7];
    const float* b2  = (const float*)d_in[8];
    const float* gam = (const float*)d_in[9];
    const float* bet = (const float*)d_in[10];
    float* o = (float*)d_out;

    hipFuncSetAttribute((const void*)ttt_m2,
                        hipFuncAttributeMaxDynamicSharedMemorySize, SMEM_BYTES);
    ttt_m2<<<64, 512, SMEM_BYTES, stream>>>(XQ, XK, XV, cf, cfl, W1, b1, W2, b2, gam, bet, o);
}

// Round 11
// 859.972 us; speedup vs baseline: 1.7411x; 1.0124x over previous
//
#include <hip/hip_runtime.h>

typedef __attribute__((ext_vector_type(8))) short bf16x8;
typedef __attribute__((ext_vector_type(4))) float f32x4;
typedef __attribute__((ext_vector_type(2))) unsigned int u32x2;
typedef __attribute__((ext_vector_type(4))) unsigned int u32x4;

#define MFMA16(a,b,c) __builtin_amdgcn_mfma_f32_16x16x32_bf16(a,b,c,0,0,0)
#define A_GELU 0.7978845608028654f

// ---- LDS byte offsets (all 16B aligned) ----
#define OFF_W1B   0u        // ushort[256][72]  W1 mirror [n=hf4][m=f]
#define OFF_W2F   36864u    // ushort[64][264]  W2 mirror [f][hf4]
#define OFF_W2T   70656u    // ushort[256][72]  W2 transposed mirror [hf4][f]
#define OFF_XK    107520u   // ushort[16][72]   xk row-major
#define OFF_XQ    109824u   // ushort[16][72]
#define OFF_XKT   112128u   // ushort[64][24]   xk col-major [f][r], r<16
#define OFF_X2    115200u   // ushort[16][264]
#define OFF_X2B   123648u   // ushort[16][264]
#define OFF_DZ2B  132096u   // ushort[16][72]
#define OFF_DZ1CT 134400u   // ushort[256][24]  dZ1 col-major [n][r]
#define OFF_DZ2CT 146688u   // ushort[64][24]
#define OFF_M1    149760u   // ushort[16][24]
#define OFF_M2    150528u   // ushort[16][24]
#define OFF_Z2F   151296u   // float[16][66]  Z2 partial (kh==1)
#define OFF_Z2G   155520u   // float[16][66]  Z2 partial (kh==0)
#define OFF_TGT   159744u   // ushort[16][72]  xv-xk bf16
#define OFF_B2    162048u   // float[2][64]
#define OFF_COEF  162560u   // float[16]
#define OFF_CL    162624u   // float[1] (+pad)
#define SMEM_BYTES 162640u

__device__ __forceinline__ float fast_tanh(float u){
    float e = __expf(2.0f*u);
    return 1.0f - 2.0f/(e + 1.0f);
}
__device__ __forceinline__ float gelu_f(float x){
    float t = fast_tanh(A_GELU*(x + 0.044715f*x*x*x));
    return 0.5f*x*(1.0f+t);
}
__device__ __forceinline__ float dgelu_f(float x){
    float x2 = x*x;
    float t = fast_tanh(A_GELU*x*(1.0f + 0.044715f*x2));
    return 0.5f*x*((1.0f-t*t)*(A_GELU + 0.1070322243f*x2)) + 0.5f*(1.0f+t);
}
__device__ __forceinline__ short f2bf(float f){
    unsigned u = __builtin_bit_cast(unsigned, f);
    u += 0x7FFFu + ((u >> 16) & 1u);
    return (short)(u >> 16);
}
__device__ __forceinline__ float bf2f(unsigned short s){
    unsigned u = ((unsigned)s) << 16;
    return __builtin_bit_cast(float, u);
}
__device__ __forceinline__ unsigned pkbf(float a, float b){
    unsigned r;
    asm("v_cvt_pk_bf16_f32 %0, %1, %2" : "=v"(r) : "v"(a), "v"(b));
    return r;
}
__device__ __forceinline__ bf16x8 ldfrag(const unsigned short* p){
    return *(const bf16x8*)p;
}
// K=16 operand in a K=32 MFMA: k>=16 slots (hi>=2 lanes) supply zeros on both
// A and B, so those products are exactly 0.
__device__ __forceinline__ bf16x8 ldmask16(const unsigned short* row, int hi){
    bf16x8 r = {0,0,0,0,0,0,0,0};
    if (hi < 2) r = *(const bf16x8*)(row + hi*8);
    return r;
}

__global__ __launch_bounds__(512, 1)
void ttt_m2(const float* __restrict__ XQ, const float* __restrict__ XK,
            const float* __restrict__ XV, const float* __restrict__ coeff,
            const float* __restrict__ coeff_last,
            const float* __restrict__ W1g, const float* __restrict__ b1g,
            const float* __restrict__ W2g, const float* __restrict__ b2g,
            const float* __restrict__ gammag, const float* __restrict__ betag,
            float* __restrict__ out)
{
    const int h  = blockIdx.x;      // head 0..63
    const int t  = threadIdx.x;     // 0..511
    const int l  = t & 63;          // lane
    const int w  = t >> 6;          // wave 0..7
    const int lo = l & 15;
    const int hi = l >> 4;          // 0..3

    extern __shared__ char smem[];
    unsigned short* sW1bu  = (unsigned short*)(smem + OFF_W1B);
    unsigned short* sW2fu  = (unsigned short*)(smem + OFF_W2F);
    unsigned short* sW2T   = (unsigned short*)(smem + OFF_W2T);
    unsigned short* sxku   = (unsigned short*)(smem + OFF_XK);
    unsigned short* sxqu   = (unsigned short*)(smem + OFF_XQ);
    unsigned short* sxkT   = (unsigned short*)(smem + OFF_XKT);
    unsigned short* sX2u   = (unsigned short*)(smem + OFF_X2);
    unsigned short* sX2bu  = (unsigned short*)(smem + OFF_X2B);
    unsigned short* sdZ2bu = (unsigned short*)(smem + OFF_DZ2B);
    unsigned short* sdZ1ct = (unsigned short*)(smem + OFF_DZ1CT);
    unsigned short* sdZ2ct = (unsigned short*)(smem + OFF_DZ2CT);
    unsigned short* sM1u   = (unsigned short*)(smem + OFF_M1);
    unsigned short* sM2u   = (unsigned short*)(smem + OFF_M2);
    float* sZ2f  = (float*)(smem + OFF_Z2F);
    float* sZ2g  = (float*)(smem + OFF_Z2G);
    unsigned short* stgtu = (unsigned short*)(smem + OFF_TGT);
    float* b2f   = (float*)(smem + OFF_B2);
    float* scoef = (float*)(smem + OFF_COEF);
    float* sCL   = (float*)(smem + OFF_CL);

    const int base1 = h*16384;   // W1 [64][256]
    const int base2 = h*16384;   // W2 [256][64]

    // ---------------- init ----------------
    float mW1[4][2][4];   // W1[m=mt*16+hi*4+reg][n=(2w+tix)*16+lo]
    float mW2T[4][2][4];  // W2T[f=ft*16+hi*4+reg][hf=(2w+tix)*16+lo] = W2[hf][f]
    #pragma unroll
    for (int mt = 0; mt < 4; ++mt)
      #pragma unroll
      for (int tix = 0; tix < 2; ++tix)
        #pragma unroll
        for (int reg = 0; reg < 4; ++reg) {
            const int m = mt*16 + hi*4 + reg, n = (2*w + tix)*16 + lo;
            mW1[mt][tix][reg] = W1g[base1 + m*256 + n];
        }
    #pragma unroll
    for (int ft = 0; ft < 4; ++ft)
      #pragma unroll
      for (int tix = 0; tix < 2; ++tix)
        #pragma unroll
        for (int reg = 0; reg < 4; ++reg) {
            const int f = ft*16 + hi*4 + reg, hf = (2*w + tix)*16 + lo;
            mW2T[ft][tix][reg] = W2g[base2 + hf*64 + f];
        }
    float b1reg[2];
    b1reg[0] = b1g[h*256 + (2*w)*16 + lo];
    b1reg[1] = b1g[h*256 + (2*w+1)*16 + lo];

    // bf16 mirrors (cooperative)
    for (int i = 0; i < 32; ++i) {
        const int idx = i*512 + t;
        const int m = idx >> 8, n = idx & 255;
        sW1bu[n*72 + m] = f2bf(W1g[base1 + idx]);
    }
    for (int i = 0; i < 32; ++i) {
        const int idx = i*512 + t;
        const int hf = idx >> 6, f = idx & 63;
        const short v = f2bf(W2g[base2 + idx]);
        sW2fu[f*264 + hf] = v;
        sW2T[hf*72 + f]   = v;
    }
    if (t < 64) b2f[t] = b2g[h*64 + t];

    const float gj = gammag[(h & 15)*64 + l];
    const float bj = betag [(h & 15)*64 + l];

    // ---- stage chunk 0 (all waves, 2 rows each) ----
    {
        const int r0 = w*2;
        const float xk0 = XK[h*1024 + r0*64 + l],     xq0 = XQ[h*1024 + r0*64 + l];
        const float xk1 = XK[h*1024 + (r0+1)*64 + l], xq1 = XQ[h*1024 + (r0+1)*64 + l];
        const float xv0 = XV[h*1024 + r0*64 + l],     xv1 = XV[h*1024 + (r0+1)*64 + l];
        const unsigned pkk = pkbf(xk0, xk1), pkq = pkbf(xq0, xq1);
        const unsigned pkt = pkbf(xv0 - xk0, xv1 - xk1);
        sxku[r0*72 + l]     = (unsigned short)pkk;
        sxku[(r0+1)*72 + l] = (unsigned short)(pkk >> 16);
        sxqu[r0*72 + l]     = (unsigned short)pkq;
        sxqu[(r0+1)*72 + l] = (unsigned short)(pkq >> 16);
        *(unsigned*)&sxkT[l*24 + r0] = pkk;
        stgtu[r0*72 + l]     = (unsigned short)pkt;
        stgtu[(r0+1)*72 + l] = (unsigned short)(pkt >> 16);
        if (t < 16)  scoef[t] = coeff[h*16 + t];
        if (t == 16) sCL[0]   = coeff_last[h];
    }
    __syncthreads();                                            // B1 (chunk 0)

    // preload W1 frags for chunk 0 (sW1bu stable until next PF-a)
    bf16x8 w1f[2][2];
    #pragma unroll
    for (int tix = 0; tix < 2; ++tix) {
        const int n = (2*w + tix)*16 + lo;
        w1f[tix][0] = ldfrag(sW1bu + n*72 + hi*8);
        w1f[tix][1] = ldfrag(sW1bu + n*72 + 32 + hi*8);
    }

    for (int ci = 0; ci < 128; ++ci) {
        // ---- snapshot coeffs to regs ----
        const float clv = sCL[0];
        const float c15 = scoef[15];
        float crs[4];
        #pragma unroll
        for (int reg = 0; reg < 4; ++reg) crs[reg] = scoef[hi*4 + reg];

        // ---- prefetch next chunk globals into regs (waves 4-7) ----
        float pxk[4], pxq[4], pxv[4];
        float pcf = 0.f, pcl = 0.f;
        if (w >= 4 && ci < 127) {
            const int cb1 = (ci + 1)*65536 + h*1024;
            const int r0 = (w - 4)*4;
            #pragma unroll
            for (int i = 0; i < 4; ++i) {
                pxk[i] = XK[cb1 + (r0 + i)*64 + l];
                pxq[i] = XQ[cb1 + (r0 + i)*64 + l];
                pxv[i] = XV[cb1 + (r0 + i)*64 + l];
            }
            const int u = t - 256;
            if (u < 16)  pcf = coeff[(ci + 1)*1024 + h*16 + u];
            if (u == 16) pcl = coeff_last[(ci + 1)*64 + h];
        }

        // ---- PA: Z1 = xk@W1 + b1 ; X2 ; wave0: A1/M1' ; W2 mirror rewrites ----
        float z1s[8];
        unsigned px2[2][2];                       // packed X2 bf16 pairs -> PF-a
        bf16x8 afk0 = ldfrag(sxku + lo*72 + hi*8);
        bf16x8 afk1 = ldfrag(sxku + lo*72 + 32 + hi*8);
        #pragma unroll
        for (int tix = 0; tix < 2; ++tix) {
            const int n = (2*w + tix)*16 + lo;
            f32x4 acc = {b1reg[tix], b1reg[tix], b1reg[tix], b1reg[tix]};
            acc = MFMA16(afk0, w1f[tix][0], acc);
            acc = MFMA16(afk1, w1f[tix][1], acc);
            float g[4];
            #pragma unroll
            for (int reg = 0; reg < 4; ++reg) {
                z1s[tix*4 + reg] = acc[reg];
                g[reg] = gelu_f(acc[reg]);
            }
            const unsigned p01 = pkbf(g[0], g[1]), p23 = pkbf(g[2], g[3]);
            px2[tix][0] = p01; px2[tix][1] = p23;
            sX2u[(hi*4+0)*264 + n] = (unsigned short)p01;
            sX2u[(hi*4+1)*264 + n] = (unsigned short)(p01 >> 16);
            sX2u[(hi*4+2)*264 + n] = (unsigned short)p23;
            sX2u[(hi*4+3)*264 + n] = (unsigned short)(p23 >> 16);
        }
        if (w == 0) {   // A1 = xq@xk^T ; M1'[r][s] = (s<=r) ? -c_r*(A1+1) : 0
            bf16x8 aq0 = ldfrag(sxqu + lo*72 + hi*8);
            bf16x8 aq1 = ldfrag(sxqu + lo*72 + 32 + hi*8);
            f32x4 a1 = {0.f, 0.f, 0.f, 0.f};
            a1 = MFMA16(aq0, afk0, a1);
            a1 = MFMA16(aq1, afk1, a1);
            #pragma unroll
            for (int reg = 0; reg < 4; ++reg) {
                const int r = hi*4 + reg;
                const float v = (lo <= r) ? (-crs[reg]*(a1[reg] + 1.0f)) : 0.0f;
                sM1u[r*24 + lo] = f2bf(v);
            }
        }
        // W2 mirror rewrites from mW2T masters
        #pragma unroll
        for (int ft = 0; ft < 4; ++ft)
          #pragma unroll
          for (int tix = 0; tix < 2; ++tix) {
                const int hf = (2*w + tix)*16 + lo, f0 = ft*16 + hi*4;
                const unsigned p01 = pkbf(mW2T[ft][tix][0], mW2T[ft][tix][1]);
                const unsigned p23 = pkbf(mW2T[ft][tix][2], mW2T[ft][tix][3]);
                *(u32x2*)&sW2T[hf*72 + f0] = (u32x2){p01, p23};
                sW2fu[(f0+0)*264 + hf] = (unsigned short)p01;
                sW2fu[(f0+1)*264 + hf] = (unsigned short)(p01 >> 16);
                sW2fu[(f0+2)*264 + hf] = (unsigned short)p23;
                sW2fu[(f0+3)*264 + hf] = (unsigned short)(p23 >> 16);
          }
        __syncthreads();                                        // B2

        // ---- PB: Z2 = X2@W2 + b2 (split-K, two partial buffers) ----
        const int tile = w & 3, kh = w >> 2;
        const int nf = tile*16 + lo;
        {
            f32x4 acc;
            if (kh == 0) {
                const float b2v = b2f[(ci & 1)*64 + nf];
                acc = (f32x4){b2v, b2v, b2v, b2v};
            } else acc = (f32x4){0.f, 0.f, 0.f, 0.f};
            #pragma unroll
            for (int s = 0; s < 4; ++s) {
                const int k = (kh*4 + s)*32 + hi*8;
                acc = MFMA16(ldfrag(sX2u + lo*264 + k),
                             ldfrag(sW2fu + nf*264 + k), acc);
            }
            float* dst = (kh == 0) ? sZ2g : sZ2f;
            #pragma unroll
            for (int reg = 0; reg < 4; ++reg)
                dst[(hi*4 + reg)*66 + nf] = acc[reg];
        }
        __syncthreads();                                        // B3

        // ---- PC: LN-fused-L2 backward (merge partials) -> dZ2 ----
        {
            float dzp[2];
            #pragma unroll
            for (int i = 0; i < 2; ++i) {
                const int r = w*2 + i;
                const float z2 = sZ2f[r*66 + l] + sZ2g[r*66 + l];
                float s1 = z2, s2 = z2*z2;
                #pragma unroll
                for (int m = 1; m < 64; m <<= 1) { s1 += __shfl_xor(s1, m); s2 += __shfl_xor(s2, m); }
                const float mu   = s1*(1.0f/64.0f);
                const float var  = s2*(1.0f/64.0f) - mu*mu;
                const float rstd = rsqrtf(var + 1e-6f);
                const float xh   = (z2 - mu)*rstd;
                const float go   = gj*xh + bj - bf2f(stgtu[r*72 + l]);
                const float gg   = go*gj;
                float u1 = gg, u2 = gg*xh;
                #pragma unroll
                for (int m = 1; m < 64; m <<= 1) { u1 += __shfl_xor(u1, m); u2 += __shfl_xor(u2, m); }
                dzp[i] = (64.0f*gg - u1 - xh*u2)*(rstd*(1.0f/64.0f));
            }
            const unsigned pk = pkbf(dzp[0], dzp[1]);
            sdZ2bu[(w*2)*72 + l]   = (unsigned short)pk;
            sdZ2bu[(w*2+1)*72 + l] = (unsigned short)(pk >> 16);
            *(unsigned*)&sdZ2ct[l*24 + w*2] = pk;
        }
        __syncthreads();                                        // B4

        // ---- PD+PE (merged; dZ1 column traffic is wave-private):
        //      dZ1 = (dZ2@W2^T)*dgelu(Z1) ; b1 carry ;
        //      Z1bar = xq@W1 + b1old + M1'@dZ1 -> X2b ; W1 master update ----
        {
            bf16x8 ad0 = ldfrag(sdZ2bu + lo*72 + hi*8);
            bf16x8 ad1 = ldfrag(sdZ2bu + lo*72 + 32 + hi*8);
            float b1old[2];
            #pragma unroll
            for (int tix = 0; tix < 2; ++tix) {
                const int n = (2*w + tix)*16 + lo;              // hf col
                f32x4 acc = {0.f, 0.f, 0.f, 0.f};
                acc = MFMA16(ad0, ldfrag(sW2T + n*72 + hi*8), acc);
                acc = MFMA16(ad1, ldfrag(sW2T + n*72 + 32 + hi*8), acc);
                float dv[4], cs = 0.f;
                #pragma unroll
                for (int reg = 0; reg < 4; ++reg) {
                    dv[reg] = acc[reg]*dgelu_f(z1s[tix*4 + reg]);
                    cs += dv[reg];
                }
                *(u32x2*)&sdZ1ct[n*24 + hi*4] =
                    (u32x2){pkbf(dv[0], dv[1]), pkbf(dv[2], dv[3])};
                cs += __shfl_xor(cs, 16);
                cs += __shfl_xor(cs, 32);
                b1old[tix] = b1reg[tix];
                b1reg[tix] -= c15*cs;
            }
            // (no barrier: sdZ1ct columns written & read by the same wave)
            bf16x8 aq0 = ldfrag(sxqu + lo*72 + hi*8);
            bf16x8 aq1 = ldfrag(sxqu + lo*72 + 32 + hi*8);
            bf16x8 am1 = ldmask16(sM1u + lo*24, hi);
            #pragma unroll
            for (int tix = 0; tix < 2; ++tix) {
                const int n = (2*w + tix)*16 + lo;
                f32x4 acc = {b1old[tix], b1old[tix], b1old[tix], b1old[tix]};
                acc = MFMA16(aq0, w1f[tix][0], acc);
                acc = MFMA16(aq1, w1f[tix][1], acc);
                acc = MFMA16(am1, ldmask16(sdZ1ct + n*24, hi), acc);
                float g[4];
                #pragma unroll
                for (int reg = 0; reg < 4; ++reg) g[reg] = gelu_f(acc[reg]);
                const unsigned p01 = pkbf(g[0], g[1]), p23 = pkbf(g[2], g[3]);
                sX2bu[(hi*4+0)*264 + n] = (unsigned short)p01;
                sX2bu[(hi*4+1)*264 + n] = (unsigned short)(p01 >> 16);
                sX2bu[(hi*4+2)*264 + n] = (unsigned short)p23;
                sX2bu[(hi*4+3)*264 + n] = (unsigned short)(p23 >> 16);
            }
            // W1 -= cl * xk^T @ dZ1  (A from sxkT frags, B from sdZ1ct frags)
            bf16x8 bz0 = ldmask16(sdZ1ct + ((2*w)*16 + lo)*24, hi);
            bf16x8 bz1 = ldmask16(sdZ1ct + ((2*w+1)*16 + lo)*24, hi);
            #pragma unroll
            for (int mt = 0; mt < 4; ++mt) {
                bf16x8 axt = ldmask16(sxkT + (mt*16 + lo)*24, hi);
                f32x4 z4 = {0.f,0.f,0.f,0.f};
                f32x4 u0 = MFMA16(axt, bz0, z4);
                f32x4 u1 = MFMA16(axt, bz1, z4);
                #pragma unroll
                for (int reg = 0; reg < 4; ++reg) {
                    mW1[mt][0][reg] -= clv*u0[reg];
                    mW1[mt][1][reg] -= clv*u1[reg];
                }
            }
        }
        __syncthreads();                                        // B6

        // ---- PF-a: W2T master update via shfl'd X2 frags ;
        //      wave0 A2/M2' ; wave1 b2 carry ; W1-mirror rewrite ----
        {
            bf16x8 bz2[4];
            #pragma unroll
            for (int nt = 0; nt < 4; ++nt)
                bz2[nt] = ldmask16(sdZ2ct + (nt*16 + lo)*24, hi);
            // X2 frags via cross-lane redistribution of px2 (no LDS traffic
            // beyond the bpermute): elem j of xf[tix] = X2[hi*8+j][(2w+tix)*16+lo]
            bf16x8 xf[2];
            {
                const int base = lo + 32*(hi & 1);
                #pragma unroll
                for (int tix = 0; tix < 2; ++tix) {
                    unsigned w0 = (unsigned)__shfl((int)px2[tix][0], base);
                    unsigned w1 = (unsigned)__shfl((int)px2[tix][1], base);
                    unsigned w2 = (unsigned)__shfl((int)px2[tix][0], base + 16);
                    unsigned w3 = (unsigned)__shfl((int)px2[tix][1], base + 16);
                    if (hi >= 2) { w0 = 0; w1 = 0; w2 = 0; w3 = 0; }
                    xf[tix] = __builtin_bit_cast(bf16x8, (u32x4){w0, w1, w2, w3});
                }
            }
            // W2T -= cl * (dZ2^T @ X2): A = dZ2 col-major frags, B = xf
            #pragma unroll
            for (int ft = 0; ft < 4; ++ft)
                #pragma unroll
                for (int tix = 0; tix < 2; ++tix) {
                    f32x4 z4 = {0.f,0.f,0.f,0.f};
                    f32x4 u = MFMA16(bz2[ft], xf[tix], z4);
                    #pragma unroll
                    for (int reg = 0; reg < 4; ++reg)
                        mW2T[ft][tix][reg] -= clv*u[reg];
                }
            if (w == 0) {   // A2 = X2b@X2^T ; M2'
                f32x4 a2 = {0.f,0.f,0.f,0.f};
                #pragma unroll
                for (int ks = 0; ks < 8; ++ks) {
                    const int k = ks*32 + hi*8;
                    a2 = MFMA16(ldfrag(sX2bu + lo*264 + k),
                                ldfrag(sX2u + lo*264 + k), a2);
                }
                #pragma unroll
                for (int reg = 0; reg < 4; ++reg) {
                    const int r = hi*4 + reg;
                    const float v = (lo <= r) ? (-crs[reg]*(a2[reg] + 1.0f)) : 0.0f;
                    sM2u[r*24 + lo] = f2bf(v);
                }
            }
            if (w == 1) {   // b2 carry (contiguous b128 reads of dZ2 col l)
                bf16x8 c0 = ldfrag(sdZ2ct + l*24);
                bf16x8 c1 = ldfrag(sdZ2ct + l*24 + 8);
                float cs = 0.f;
                #pragma unroll
                for (int j = 0; j < 8; ++j)
                    cs += bf2f((unsigned short)c0[j]) + bf2f((unsigned short)c1[j]);
                b2f[((ci + 1) & 1)*64 + l] = b2f[(ci & 1)*64 + l] - c15*cs;
            }
            // W1-mirror rewrite (sW1bu last read via w1f preload)
            #pragma unroll
            for (int mt = 0; mt < 4; ++mt)
              #pragma unroll
              for (int tix = 0; tix < 2; ++tix) {
                    const int n = (2*w + tix)*16 + lo, m0 = mt*16 + hi*4;
                    *(u32x2*)&sW1bu[n*72 + m0] =
                        (u32x2){pkbf(mW1[mt][tix][0], mW1[mt][tix][1]),
                                pkbf(mW1[mt][tix][2], mW1[mt][tix][3])};
              }
        }
        __syncthreads();                                        // B7

        // ---- PF-b: reload W1 frags (mirror stable until next PF-a) ;
        //      waves 0-3 Z2bar full-K + out ; waves 4-7 stage next chunk ----
        #pragma unroll
        for (int tix = 0; tix < 2; ++tix) {
            const int n = (2*w + tix)*16 + lo;
            w1f[tix][0] = ldfrag(sW1bu + n*72 + hi*8);
            w1f[tix][1] = ldfrag(sW1bu + n*72 + 32 + hi*8);
        }
        if (w < 4) {
            const int nf2 = w*16 + lo;
            const float b2v = b2f[(ci & 1)*64 + nf2];
            f32x4 acc = {b2v, b2v, b2v, b2v};
            #pragma unroll
            for (int s = 0; s < 8; ++s) {
                const int k0 = s*32 + hi*8;
                acc = MFMA16(ldfrag(sX2bu + lo*264 + k0),
                             ldfrag(sW2fu + nf2*264 + k0), acc);
            }
            acc = MFMA16(ldmask16(sM2u + lo*24, hi),
                         ldmask16(sdZ2ct + nf2*24, hi), acc);
            #pragma unroll
            for (int reg = 0; reg < 4; ++reg)
                out[h*131072 + (ci*16 + hi*4 + reg)*64 + nf2] = acc[reg];
        } else if (ci < 127) {
            const int r0 = (w - 4)*4;
            #pragma unroll
            for (int p = 0; p < 2; ++p) {
                const int r = r0 + 2*p;
                const unsigned pkk = pkbf(pxk[2*p], pxk[2*p+1]);
                const unsigned pkq = pkbf(pxq[2*p], pxq[2*p+1]);
                const unsigned pkt = pkbf(pxv[2*p] - pxk[2*p], pxv[2*p+1] - pxk[2*p+1]);
                sxku[r*72 + l]     = (unsigned short)pkk;
                sxku[(r+1)*72 + l] = (unsigned short)(pkk >> 16);
                sxqu[r*72 + l]     = (unsigned short)pkq;
                sxqu[(r+1)*72 + l] = (unsigned short)(pkq >> 16);
                *(unsigned*)&sxkT[l*24 + r] = pkk;
                stgtu[r*72 + l]     = (unsigned short)pkt;
                stgtu[(r+1)*72 + l] = (unsigned short)(pkt >> 16);
            }
            const int u = t - 256;
            if (u < 16)  scoef[u] = pcf;
            if (u == 16) sCL[0]   = pcl;
        }
        __syncthreads();                                        // B1 (next chunk)
    }
}

extern "C" void kernel_launch(void* const* d_in, const int* in_sizes, int n_in,
                              void* d_out, int out_size, void* d_ws, size_t ws_size,
                              hipStream_t stream) {
    const float* XQ  = (const float*)d_in[0];
    const float* XK  = (const float*)d_in[1];
    const float* XV  = (const float*)d_in[2];
    const float* cf  = (const float*)d_in[3];
    const float* cfl = (const float*)d_in[4];
    const float* W1  = (const float*)d_in[5];
    const float* b1  = (const float*)d_in[6];
    const float* W2  = (const float*)d_in[7];
    const float* b2  = (const float*)d_in[8];
    const float* gam = (const float*)d_in[9];
    const float* bet = (const float*)d_in[10];
    float* o = (float*)d_out;

    hipFuncSetAttribute((const void*)ttt_m2,
                        hipFuncAttributeMaxDynamicSharedMemorySize, SMEM_BYTES);
    ttt_m2<<<64, 512, SMEM_BYTES, stream>>>(XQ, XK, XV, cf, cfl, W1, b1, W2, b2, gam, bet, o);
}